// Round 1
// baseline (216.536 us; speedup 1.0000x reference)
//
#include <hip/hip_runtime.h>
#include <math.h>

// Problem: x shape (8, 32, 512, 512) f32. Outputs: (dilated = 3x3 max, eroded = 3x3 min),
// 'same' size, border = reduce over valid pixels only (identity-padded).
// N*C = 256 planes of 512x512.

#define IMG_W 512
#define IMG_H 512

__global__ __launch_bounds__(256) void erode_dilate_kernel(
    const float* __restrict__ x,
    float* __restrict__ dil,
    float* __restrict__ ero)
{
    // Each thread: 4 consecutive output pixels in one row.
    // 128 quads per row, 512 rows per plane -> 65536 threads per plane.
    const int tid = blockIdx.x * blockDim.x + threadIdx.x;
    const int x0  = (tid & 127) << 2;        // 0, 4, ..., 508
    const int y   = (tid >> 7) & 511;
    const int p   = tid >> 16;               // plane 0..255

    const float* plane = x + (size_t)p * (IMG_W * IMG_H);

    float mx0 = -INFINITY, mx1 = -INFINITY, mx2 = -INFINITY, mx3 = -INFINITY;
    float mn0 =  INFINITY, mn1 =  INFINITY, mn2 =  INFINITY, mn3 =  INFINITY;

    #pragma unroll
    for (int dy = -1; dy <= 1; ++dy) {
        const int yy = y + dy;
        if (yy < 0 || yy >= IMG_H) continue;
        const float* row = plane + yy * IMG_W;

        const float4 v = *reinterpret_cast<const float4*>(row + x0);
        float lmax, lmin, rmax, rmin;
        if (x0 > 0) {
            const float l = row[x0 - 1];
            lmax = l; lmin = l;
        } else {
            lmax = -INFINITY; lmin = INFINITY;
        }
        if (x0 + 4 < IMG_W) {
            const float r = row[x0 + 4];
            rmax = r; rmin = r;
        } else {
            rmax = -INFINITY; rmin = INFINITY;
        }

        // horizontal 3-max / 3-min for the 4 output positions
        const float hx0 = fmaxf(fmaxf(lmax, v.x), v.y);
        const float hx1 = fmaxf(fmaxf(v.x,  v.y), v.z);
        const float hx2 = fmaxf(fmaxf(v.y,  v.z), v.w);
        const float hx3 = fmaxf(fmaxf(v.z,  v.w), rmax);

        const float hn0 = fminf(fminf(lmin, v.x), v.y);
        const float hn1 = fminf(fminf(v.x,  v.y), v.z);
        const float hn2 = fminf(fminf(v.y,  v.z), v.w);
        const float hn3 = fminf(fminf(v.z,  v.w), rmin);

        // vertical accumulate
        mx0 = fmaxf(mx0, hx0); mx1 = fmaxf(mx1, hx1);
        mx2 = fmaxf(mx2, hx2); mx3 = fmaxf(mx3, hx3);
        mn0 = fminf(mn0, hn0); mn1 = fminf(mn1, hn1);
        mn2 = fminf(mn2, hn2); mn3 = fminf(mn3, hn3);
    }

    const size_t o = (size_t)p * (IMG_W * IMG_H) + (size_t)y * IMG_W + x0;
    *reinterpret_cast<float4*>(dil + o) = make_float4(mx0, mx1, mx2, mx3);
    *reinterpret_cast<float4*>(ero + o) = make_float4(mn0, mn1, mn2, mn3);
}

extern "C" void kernel_launch(void* const* d_in, const int* in_sizes, int n_in,
                              void* d_out, int out_size, void* d_ws, size_t ws_size,
                              hipStream_t stream) {
    const float* x = (const float*)d_in[0];
    float* out = (float*)d_out;

    const size_t n_elems = (size_t)8 * 32 * 512 * 512;  // 67,108,864
    float* dil = out;
    float* ero = out + n_elems;

    const int total_threads = (int)(n_elems / 4);       // 16,777,216
    const int block = 256;
    const int grid = total_threads / block;             // 65,536

    erode_dilate_kernel<<<grid, block, 0, stream>>>(x, dil, ero);
}

// Round 2
// 181.962 us; speedup vs baseline: 1.1900x; 1.1900x over previous
//
#include <hip/hip_runtime.h>
#include <math.h>

// x: (8, 32, 512, 512) f32 -> (dilated = 3x3 max, eroded = 3x3 min), 'same',
// borders reduce over valid pixels only (identity padding with -inf/+inf).
// 256 planes of 512x512.

#define IMG_W 512
#define IMG_H 512
#define PLANE (IMG_W * IMG_H)
#define ROWS_PER_THREAD 8

__device__ __forceinline__ void load_hrow(const float* __restrict__ row, int x0,
                                          float4& hx, float4& hn) {
    const float4 v = *reinterpret_cast<const float4*>(row + x0);
    float lmax, lmin, rmax, rmin;
    if (x0 > 0) {
        const float l = row[x0 - 1];
        lmax = l; lmin = l;
    } else {
        lmax = -INFINITY; lmin = INFINITY;
    }
    if (x0 < IMG_W - 4) {
        const float r = row[x0 + 4];
        rmax = r; rmin = r;
    } else {
        rmax = -INFINITY; rmin = INFINITY;
    }
    hx.x = fmaxf(fmaxf(lmax, v.x), v.y);
    hx.y = fmaxf(fmaxf(v.x,  v.y), v.z);
    hx.z = fmaxf(fmaxf(v.y,  v.z), v.w);
    hx.w = fmaxf(fmaxf(v.z,  v.w), rmax);
    hn.x = fminf(fminf(lmin, v.x), v.y);
    hn.y = fminf(fminf(v.x,  v.y), v.z);
    hn.z = fminf(fminf(v.y,  v.z), v.w);
    hn.w = fminf(fminf(v.z,  v.w), rmin);
}

__global__ __launch_bounds__(256) void erode_dilate_kernel(
    const float* __restrict__ x,
    float* __restrict__ dil,
    float* __restrict__ ero)
{
    // Thread tile: 4 wide x 8 tall. 128 x-quads per row; 64 row-groups per plane.
    // 8192 threads per plane (2^13), 256 planes -> 2,097,152 threads, 8192 blocks.
    const int tid = blockIdx.x * blockDim.x + threadIdx.x;
    const int x0  = (tid & 127) << 2;          // 0..508
    const int y0  = ((tid >> 7) & 63) << 3;    // 0, 8, ..., 504
    const int p   = tid >> 13;                 // plane 0..255

    const float* plane = x + (size_t)p * PLANE;

    const float4 NEGI = make_float4(-INFINITY, -INFINITY, -INFINITY, -INFINITY);
    const float4 POSI = make_float4( INFINITY,  INFINITY,  INFINITY,  INFINITY);

    // Rolling 3-row window of horizontal min/max results.
    float4 hx0, hn0, hx1, hn1, hx2, hn2;

    if (y0 > 0) {
        load_hrow(plane + (size_t)(y0 - 1) * IMG_W, x0, hx0, hn0);
    } else {
        hx0 = NEGI; hn0 = POSI;
    }
    load_hrow(plane + (size_t)y0 * IMG_W, x0, hx1, hn1);

    size_t o = (size_t)p * PLANE + (size_t)y0 * IMG_W + x0;

    #pragma unroll
    for (int r = 0; r < ROWS_PER_THREAD; ++r) {
        const int yy = y0 + r + 1;
        if (yy < IMG_H) {
            load_hrow(plane + (size_t)yy * IMG_W, x0, hx2, hn2);
        } else {
            hx2 = NEGI; hn2 = POSI;
        }

        float4 d, e;
        d.x = fmaxf(fmaxf(hx0.x, hx1.x), hx2.x);
        d.y = fmaxf(fmaxf(hx0.y, hx1.y), hx2.y);
        d.z = fmaxf(fmaxf(hx0.z, hx1.z), hx2.z);
        d.w = fmaxf(fmaxf(hx0.w, hx1.w), hx2.w);
        e.x = fminf(fminf(hn0.x, hn1.x), hn2.x);
        e.y = fminf(fminf(hn0.y, hn1.y), hn2.y);
        e.z = fminf(fminf(hn0.z, hn1.z), hn2.z);
        e.w = fminf(fminf(hn0.w, hn1.w), hn2.w);

        *reinterpret_cast<float4*>(dil + o) = d;
        *reinterpret_cast<float4*>(ero + o) = e;
        o += IMG_W;

        hx0 = hx1; hn0 = hn1;
        hx1 = hx2; hn1 = hn2;
    }
}

extern "C" void kernel_launch(void* const* d_in, const int* in_sizes, int n_in,
                              void* d_out, int out_size, void* d_ws, size_t ws_size,
                              hipStream_t stream) {
    const float* x = (const float*)d_in[0];
    float* out = (float*)d_out;

    const size_t n_elems = (size_t)8 * 32 * 512 * 512;  // 67,108,864
    float* dil = out;
    float* ero = out + n_elems;

    const int total_threads = (int)(n_elems / (4 * ROWS_PER_THREAD));  // 2,097,152
    const int block = 256;
    const int grid = total_threads / block;                            // 8192

    erode_dilate_kernel<<<grid, block, 0, stream>>>(x, dil, ero);
}